// Round 5
// baseline (1101.814 us; speedup 1.0000x reference)
//
#include <hip/hip_runtime.h>
#include <math.h>
#include <stdint.h>

#define B_N 32768
#define V_N 2048
#define H_N 256
#define E_N 16
#define Q_N 4

// RNG variant: 1 = jax_threefry_partitionable (modern default). Proven passing r4.
#define RNG_PART 1

// ---------------- Threefry2x32 (JAX-exact, 20 rounds; KAT-verified on HW r2) ----------------
#define TF_R(x0,x1,r) { x0 += x1; x1 = ((x1 << (r)) | (x1 >> (32-(r)))); x1 ^= x0; }

__device__ __forceinline__ void tf_block(uint32_t k0, uint32_t k1, uint32_t &x0, uint32_t &x1){
  uint32_t k2 = k0 ^ k1 ^ 0x1BD11BDAu;
  x0 += k0; x1 += k1;
  TF_R(x0,x1,13) TF_R(x0,x1,15) TF_R(x0,x1,26) TF_R(x0,x1,6)
  x0 += k1; x1 += k2 + 1u;
  TF_R(x0,x1,17) TF_R(x0,x1,29) TF_R(x0,x1,16) TF_R(x0,x1,24)
  x0 += k2; x1 += k0 + 2u;
  TF_R(x0,x1,13) TF_R(x0,x1,15) TF_R(x0,x1,26) TF_R(x0,x1,6)
  x0 += k0; x1 += k1 + 3u;
  TF_R(x0,x1,17) TF_R(x0,x1,29) TF_R(x0,x1,16) TF_R(x0,x1,24)
  x0 += k1; x1 += k2 + 4u;
  TF_R(x0,x1,13) TF_R(x0,x1,15) TF_R(x0,x1,26) TF_R(x0,x1,6)
  x0 += k2; x1 += k0 + 5u;
}

__device__ __forceinline__ int run_kats(){
  uint32_t x0, x1;
  x0 = 0u; x1 = 0u;
  tf_block(0u, 0u, x0, x1);
  if (x0 != 0x6b200159u || x1 != 0x99ba4efeu) return 1;
  x0 = 0xFFFFFFFFu; x1 = 0xFFFFFFFFu;
  tf_block(0xFFFFFFFFu, 0xFFFFFFFFu, x0, x1);
  if (x0 != 0x1cb996fcu || x1 != 0xbb002be7u) return 2;
  x0 = 0x243f6a88u; x1 = 0x85a308d3u;
  tf_block(0x13198a2eu, 0x03707344u, x0, x1);
  if (x0 != 0xc4923a9cu || x1 != 0x483df7a0u) return 3;
  return 0;
}

// random_bits(key, 32, (32768,))[b]
__device__ __forceinline__ uint32_t rbits(uint32_t ka, uint32_t kb, uint32_t b){
#if RNG_PART
  uint32_t x0 = 0u, x1 = b;
  tf_block(ka, kb, x0, x1);
  return x0 ^ x1;
#else
  uint32_t i = b & 16383u;
  uint32_t x0 = i, x1 = i + 16384u;
  tf_block(ka, kb, x0, x1);
  return (b < 16384u) ? x0 : x1;
#endif
}

// ---------------- S0: per-step keys + temperature schedule + KAT flag ----------------
__global__ void s0_kernel(unsigned* __restrict__ wsu, float log_ratio){
#pragma clang fp contract(off)
  int t = threadIdx.x;
  uint32_t ka = 0u, kb = 1u;  // jax.random.key(1) == (0,1)
  uint32_t kinit0, kinit1, kl0, kl1;
#if RNG_PART
  { uint32_t a0=0u,a1=0u; tf_block(ka,kb,a0,a1); kinit0=a0; kinit1=a1; }
  { uint32_t a0=0u,a1=1u; tf_block(ka,kb,a0,a1); kl0=a0; kl1=a1; }
#else
  { uint32_t c00=0u,c01=2u; tf_block(ka,kb,c00,c01);
    uint32_t c10=1u,c11=3u; tf_block(ka,kb,c10,c11);
    kinit0=c00; kinit1=c10; kl0=c01; kl1=c11; }
#endif
  if (t == 0){
    wsu[502] = (unsigned)run_kats();
#if RNG_PART
    uint32_t x0=0u, x1=1u; tf_block(kinit0,kinit1,x0,x1);
    wsu[500]=x0; wsu[501]=x1;
#else
    uint32_t e00=0u,e01=2u; tf_block(kinit0,kinit1,e00,e01);
    uint32_t e10=1u,e11=3u; tf_block(kinit0,kinit1,e10,e11);
    wsu[500]=e01; wsu[501]=e11;
#endif
  }
  if (t < 100){
    uint32_t kt0=0u, kt1=(uint32_t)t; tf_block(kl0,kl1,kt0,kt1);   // fold_in(kloop, t)
    uint32_t q0, q1, v0, v1;
#if RNG_PART
    uint32_t p0=0u,p1=0u; tf_block(kt0,kt1,p0,p1);    // kp = split(kt)[0]
    uint32_t u0=0u,u1=1u; tf_block(kt0,kt1,u0,u1);    // ku = split(kt)[1]
    { uint32_t a=0u,b=1u; tf_block(p0,p1,a,b); q0=a; q1=b; }   // split(kp)[1]
    { uint32_t a=0u,b=1u; tf_block(u0,u1,a,b); v0=a; v1=b; }   // fold_in(ku,1)
#else
    uint32_t d00=0u,d01=2u; tf_block(kt0,kt1,d00,d01);
    uint32_t d10=1u,d11=3u; tf_block(kt0,kt1,d10,d11);
    uint32_t kp0=d00, kp1=d10, ku0=d01, ku1k=d11;
    uint32_t e00=0u,e01=2u; tf_block(kp0,kp1,e00,e01);
    uint32_t e10=1u,e11=3u; tf_block(kp0,kp1,e10,e11);
    q0=e01; q1=e11;
    { uint32_t a=0u,b=1u; tf_block(ku0,ku1k,a,b); v0=a; v1=b; }
#endif
    float fr = (float)t / 99.0f;
    float arg = log_ratio * fr;
    float T = (float)exp((double)arg);
    wsu[t*5+0]=q0; wsu[t*5+1]=q1; wsu[t*5+2]=v0; wsu[t*5+3]=v1;
    wsu[t*5+4]=__float_as_uint(T);
  }
}

// ---------------- KE: fused energies pipeline (bit-identical to r4 pass) ----------------
// enc = f32(tanh(x@We + be))  [f64 acc]; t2 = f32(enc@W1e) [f64 acc];
// h = tanh(tanh(t2+W1i+b1));  energies = 3*tanh(sum_q h*w2 + b2); logits = -softplus(it)*e
// r5 perf change: x-tile staged in LDS as f64 (cvt once at fill, exact) —
// removes 128 v_cvt_f64_f32 per strip per thread; FMA order unchanged.
__global__ __launch_bounds__(256, 4) void ke_kernel(
    const float* __restrict__ x, const float* __restrict__ We,
    const float* __restrict__ be, const float* __restrict__ W1,
    const float* __restrict__ b1, const float* __restrict__ w2,
    const float* __restrict__ b2, const float* __restrict__ invt,
    float* __restrict__ energ, float* __restrict__ logit){
#pragma clang fp contract(off)
  __shared__ double xs_d[32*16];
  __shared__ float enc_s[32*257];
  __shared__ float t2_s[32*4];
  const int tid = threadIdx.x;
  const int row0 = blockIdx.x * 32;
  const int rg = tid >> 6;           // 4 row-groups of 8 rows
  const int c0 = (tid & 63) * 4;     // 4 consecutive H-columns per thread
  double acc[8][4];
  #pragma unroll
  for (int r=0;r<8;++r){ acc[r][0]=0.0; acc[r][1]=0.0; acc[r][2]=0.0; acc[r][3]=0.0; }

  // fill indices (hoisted)
  const int fr0 = tid >> 4,  fc0 = tid & 15;          // element tid
  const int fr1 = (tid+256) >> 4, fc1 = tid & 15;     // element tid+256
  const size_t xbase = (size_t)row0 * V_N;

  for (int v0=0; v0<V_N; v0+=16){
    xs_d[fr0*16+fc0] = (double)x[xbase + (size_t)fr0*V_N + v0 + fc0];
    xs_d[fr1*16+fc1] = (double)x[xbase + (size_t)fr1*V_N + v0 + fc1];
    __syncthreads();
    const float* wp = We + (size_t)v0*H_N + c0;
    const double* xrow = xs_d + rg*8*16;
    #pragma unroll
    for (int vv=0; vv<16; ++vv){
      float4 wv = *(const float4*)wp;
      wp += H_N;
      double w0=(double)wv.x, w1=(double)wv.y, w2d=(double)wv.z, w3=(double)wv.w;
      double xv[8];
      #pragma unroll
      for (int r8=0;r8<8;++r8) xv[r8] = xrow[r8*16 + vv];
      #pragma unroll
      for (int r8=0;r8<8;++r8){
        acc[r8][0] = fma(xv[r8], w0, acc[r8][0]);
        acc[r8][1] = fma(xv[r8], w1, acc[r8][1]);
        acc[r8][2] = fma(xv[r8], w2d, acc[r8][2]);
        acc[r8][3] = fma(xv[r8], w3, acc[r8][3]);
      }
    }
    __syncthreads();
  }
  #pragma unroll
  for (int r8=0;r8<8;++r8){
    int r = rg*8 + r8;
    #pragma unroll
    for (int j=0;j<4;++j){
      int c = c0 + j;
      float m1 = (float)(acc[r8][j] + (double)be[c]);   // f32 array boundary
      enc_s[r*257 + c] = (float)tanh((double)m1);        // libm tanh, f32 store
    }
  }
  __syncthreads();
  if (tid < 128){
    int r = tid >> 2, q = tid & 3;
    double s = 0.0;
    for (int h=0; h<H_N; ++h)
      s = fma((double)enc_s[r*257+h], (double)W1[h*4+q], s);
    t2_s[r*4+q] = (float)s;                              // f32 array boundary
  }
  __syncthreads();
  float nbeta = -(float)log1p(exp((double)invt[0]));     // -softplus(inv_temp)
  for (int p=0;p<2;++p){
    int id = tid + p*256;
    int r = id >> 4, e = id & 15;
    float y = 0.0f;
    #pragma unroll
    for (int q=0;q<4;++q){
      float a1 = t2_s[r*4+q] + W1[(H_N+e)*4+q];
      float a2 = a1 + b1[q];
      float hin  = (float)tanh((double)a2);              // inner tanh
      float hout = (float)tanh((double)hin);             // outer tanh (nested in ref)
      y = y + hout * w2[q];
    }
    float yb = y + b2[0];
    float en = 3.0f * (float)tanh((double)yb);
    size_t gi = (size_t)(row0 + r)*E_N + e;
    energ[gi] = en;
    logit[gi] = nbeta * en;
  }
}

// ---------------- SAMP: annealed Metropolis chain + one-hot write ----------------
__global__ __launch_bounds__(256) void samp_kernel(
    const float* __restrict__ energ, const unsigned* __restrict__ wsu,
    float* __restrict__ probs){
#pragma clang fp contract(off)
  __shared__ float se[256*16];
  const int lt = threadIdx.x;
  const int b = blockIdx.x*256 + lt;

  unsigned flag = wsu[502];
  if (flag != 0u){
    float c = 0.10f + 0.05f * (float)flag;
    float* op = probs + (size_t)b*E_N;
    #pragma unroll
    for (int j0=0; j0<16; j0+=4){
      float4 r; r.x=c; r.y=c; r.z=c; r.w=c;
      *(float4*)(op + j0) = r;
    }
    return;
  }

  float4* sv = (float4*)(se + lt*16);
  const float4* er = (const float4*)(energ + (size_t)b*E_N);
  sv[0]=er[0]; sv[1]=er[1]; sv[2]=er[2]; sv[3]=er[3];

  uint32_t k20 = wsu[500], k21 = wsu[501];
  uint32_t cur = rbits(k20, k21, (uint32_t)b) & 15u;

  for (int t=0; t<100; ++t){
    uint32_t pa=wsu[t*5+0], pb=wsu[t*5+1], ua=wsu[t*5+2], ub=wsu[t*5+3];
    float T = __uint_as_float(wsu[t*5+4]);
    uint32_t prop = rbits(pa, pb, (uint32_t)b) & 15u;
    uint32_t ru   = rbits(ua, ub, (uint32_t)b);
    float u = __uint_as_float((ru >> 9) | 0x3f800000u) - 1.0f;
    float ec = se[lt*16 + (int)cur];
    float ep = se[lt*16 + (int)prop];
    float d = ep - ec;
    float z = (-d) / T;
    z = fminf(z, 0.0f);
    float a = (float)exp((double)z);     // correctly-rounded f32 exp
    cur = (u < a) ? prop : cur;
  }
  float* op = probs + (size_t)b*E_N;
  #pragma unroll
  for (int j0=0; j0<16; j0+=4){
    float4 r;
    r.x = (cur == (uint32_t)(j0+0)) ? 1.0f : 0.0f;
    r.y = (cur == (uint32_t)(j0+1)) ? 1.0f : 0.0f;
    r.z = (cur == (uint32_t)(j0+2)) ? 1.0f : 0.0f;
    r.w = (cur == (uint32_t)(j0+3)) ? 1.0f : 0.0f;
    *(float4*)(op + j0) = r;
  }
}

extern "C" void kernel_launch(void* const* d_in, const int* in_sizes, int n_in,
                              void* d_out, int out_size, void* d_ws, size_t ws_size,
                              hipStream_t stream) {
  const float* x   = (const float*)d_in[0];
  const float* We  = (const float*)d_in[1];
  const float* be  = (const float*)d_in[2];
  const float* W1  = (const float*)d_in[3];
  const float* b1  = (const float*)d_in[4];
  const float* w2  = (const float*)d_in[5];
  const float* b2  = (const float*)d_in[6];
  const float* itp = (const float*)d_in[7];
  float* out = (float*)d_out;
  float* probs = out;
  float* energ = out + (size_t)B_N*E_N;
  float* logit = out + 2*(size_t)B_N*E_N;
  unsigned* wsu = (unsigned*)d_ws;

  float log_ratio = (float)log((double)((float)0.1));

  hipLaunchKernelGGL(s0_kernel, dim3(1), dim3(128), 0, stream, wsu, log_ratio);
  hipLaunchKernelGGL(ke_kernel, dim3(B_N/32), dim3(256), 0, stream,
                     x, We, be, W1, b1, w2, b2, itp, energ, logit);
  hipLaunchKernelGGL(samp_kernel, dim3(B_N/256), dim3(256), 0, stream,
                     energ, wsu, probs);
}

// Round 6
// 915.140 us; speedup vs baseline: 1.2040x; 1.2040x over previous
//
#include <hip/hip_runtime.h>
#include <math.h>
#include <stdint.h>

#define B_N 32768
#define V_N 2048
#define H_N 256
#define E_N 16
#define Q_N 4

// RNG variant: 1 = jax_threefry_partitionable (modern default). Proven passing r4/r5.
#define RNG_PART 1

// ---------------- Threefry2x32 (JAX-exact, 20 rounds; KAT-verified on HW r2) ----------------
#define TF_R(x0,x1,r) { x0 += x1; x1 = ((x1 << (r)) | (x1 >> (32-(r)))); x1 ^= x0; }

__device__ __forceinline__ void tf_block(uint32_t k0, uint32_t k1, uint32_t &x0, uint32_t &x1){
  uint32_t k2 = k0 ^ k1 ^ 0x1BD11BDAu;
  x0 += k0; x1 += k1;
  TF_R(x0,x1,13) TF_R(x0,x1,15) TF_R(x0,x1,26) TF_R(x0,x1,6)
  x0 += k1; x1 += k2 + 1u;
  TF_R(x0,x1,17) TF_R(x0,x1,29) TF_R(x0,x1,16) TF_R(x0,x1,24)
  x0 += k2; x1 += k0 + 2u;
  TF_R(x0,x1,13) TF_R(x0,x1,15) TF_R(x0,x1,26) TF_R(x0,x1,6)
  x0 += k0; x1 += k1 + 3u;
  TF_R(x0,x1,17) TF_R(x0,x1,29) TF_R(x0,x1,16) TF_R(x0,x1,24)
  x0 += k1; x1 += k2 + 4u;
  TF_R(x0,x1,13) TF_R(x0,x1,15) TF_R(x0,x1,26) TF_R(x0,x1,6)
  x0 += k2; x1 += k0 + 5u;
}

__device__ __forceinline__ int run_kats(){
  uint32_t x0, x1;
  x0 = 0u; x1 = 0u;
  tf_block(0u, 0u, x0, x1);
  if (x0 != 0x6b200159u || x1 != 0x99ba4efeu) return 1;
  x0 = 0xFFFFFFFFu; x1 = 0xFFFFFFFFu;
  tf_block(0xFFFFFFFFu, 0xFFFFFFFFu, x0, x1);
  if (x0 != 0x1cb996fcu || x1 != 0xbb002be7u) return 2;
  x0 = 0x243f6a88u; x1 = 0x85a308d3u;
  tf_block(0x13198a2eu, 0x03707344u, x0, x1);
  if (x0 != 0xc4923a9cu || x1 != 0x483df7a0u) return 3;
  return 0;
}

// random_bits(key, 32, (32768,))[b]
__device__ __forceinline__ uint32_t rbits(uint32_t ka, uint32_t kb, uint32_t b){
#if RNG_PART
  uint32_t x0 = 0u, x1 = b;
  tf_block(ka, kb, x0, x1);
  return x0 ^ x1;
#else
  uint32_t i = b & 16383u;
  uint32_t x0 = i, x1 = i + 16384u;
  tf_block(ka, kb, x0, x1);
  return (b < 16384u) ? x0 : x1;
#endif
}

// ---------------- S0: per-step keys + temperature schedule + KAT flag ----------------
__global__ void s0_kernel(unsigned* __restrict__ wsu, float log_ratio){
#pragma clang fp contract(off)
  int t = threadIdx.x;
  uint32_t ka = 0u, kb = 1u;  // jax.random.key(1) == (0,1)
  uint32_t kinit0, kinit1, kl0, kl1;
#if RNG_PART
  { uint32_t a0=0u,a1=0u; tf_block(ka,kb,a0,a1); kinit0=a0; kinit1=a1; }
  { uint32_t a0=0u,a1=1u; tf_block(ka,kb,a0,a1); kl0=a0; kl1=a1; }
#else
  { uint32_t c00=0u,c01=2u; tf_block(ka,kb,c00,c01);
    uint32_t c10=1u,c11=3u; tf_block(ka,kb,c10,c11);
    kinit0=c00; kinit1=c10; kl0=c01; kl1=c11; }
#endif
  if (t == 0){
    wsu[502] = (unsigned)run_kats();
#if RNG_PART
    uint32_t x0=0u, x1=1u; tf_block(kinit0,kinit1,x0,x1);
    wsu[500]=x0; wsu[501]=x1;
#else
    uint32_t e00=0u,e01=2u; tf_block(kinit0,kinit1,e00,e01);
    uint32_t e10=1u,e11=3u; tf_block(kinit0,kinit1,e10,e11);
    wsu[500]=e01; wsu[501]=e11;
#endif
  }
  if (t < 100){
    uint32_t kt0=0u, kt1=(uint32_t)t; tf_block(kl0,kl1,kt0,kt1);   // fold_in(kloop, t)
    uint32_t q0, q1, v0, v1;
#if RNG_PART
    uint32_t p0=0u,p1=0u; tf_block(kt0,kt1,p0,p1);    // kp = split(kt)[0]
    uint32_t u0=0u,u1=1u; tf_block(kt0,kt1,u0,u1);    // ku = split(kt)[1]
    { uint32_t a=0u,b=1u; tf_block(p0,p1,a,b); q0=a; q1=b; }   // split(kp)[1]
    { uint32_t a=0u,b=1u; tf_block(u0,u1,a,b); v0=a; v1=b; }   // fold_in(ku,1)
#else
    uint32_t d00=0u,d01=2u; tf_block(kt0,kt1,d00,d01);
    uint32_t d10=1u,d11=3u; tf_block(kt0,kt1,d10,d11);
    uint32_t kp0=d00, kp1=d10, ku0=d01, ku1k=d11;
    uint32_t e00=0u,e01=2u; tf_block(kp0,kp1,e00,e01);
    uint32_t e10=1u,e11=3u; tf_block(kp0,kp1,e10,e11);
    q0=e01; q1=e11;
    { uint32_t a=0u,b=1u; tf_block(ku0,ku1k,a,b); v0=a; v1=b; }
#endif
    float fr = (float)t / 99.0f;
    float arg = log_ratio * fr;
    float T = (float)exp((double)arg);
    wsu[t*5+0]=q0; wsu[t*5+1]=q1; wsu[t*5+2]=v0; wsu[t*5+3]=v1;
    wsu[t*5+4]=__float_as_uint(T);
  }
}

// ---------------- KE: fused energies pipeline (arithmetic bit-identical to r4/r5) ----------------
// enc = f32(tanh(x@We + be))  [f64 acc]; t2 = f32(enc@W1e) [f64 acc];
// h = tanh(tanh(t2+W1i+b1));  energies = 3*tanh(sum_q h*w2 + b2); logits = -softplus(it)*e
// r6: f64 LDS x-tile (cvt once, exact) + double2 broadcast reads + vv-pair inner loop.
// NO min-occupancy launch_bounds (r5's (256,4) forced VGPR=64 -> acc spilled -> 203MB scratch writes).
__global__ __launch_bounds__(256) void ke_kernel(
    const float* __restrict__ x, const float* __restrict__ We,
    const float* __restrict__ be, const float* __restrict__ W1,
    const float* __restrict__ b1, const float* __restrict__ w2,
    const float* __restrict__ b2, const float* __restrict__ invt,
    float* __restrict__ energ, float* __restrict__ logit){
#pragma clang fp contract(off)
  __shared__ double xs_d[32*16];
  __shared__ float enc_s[32*257];
  __shared__ float t2_s[32*4];
  const int tid = threadIdx.x;
  const int row0 = blockIdx.x * 32;
  const int rg = tid >> 6;           // 4 row-groups of 8 rows (wave == row-group)
  const int c0 = (tid & 63) * 4;     // 4 consecutive H-columns per thread
  double acc[8][4];
  #pragma unroll
  for (int r=0;r<8;++r){ acc[r][0]=0.0; acc[r][1]=0.0; acc[r][2]=0.0; acc[r][3]=0.0; }

  const int fr0 = tid >> 4,       fc0 = tid & 15;   // element tid       (rows 0..15)
  const int fr1 = (tid+256) >> 4;                   // element tid+256   (rows 16..31)
  const size_t xbase = (size_t)row0 * V_N;

  for (int v0=0; v0<V_N; v0+=16){
    // fill x-tile as f64 (cvt is exact; done once per element)
    xs_d[tid]       = (double)x[xbase + (size_t)fr0*V_N + v0 + fc0];
    xs_d[tid + 256] = (double)x[xbase + (size_t)fr1*V_N + v0 + fc0];
    __syncthreads();
    const float* wp = We + (size_t)v0*H_N + c0;
    const double* xrow = xs_d + rg*128;   // this wave's 8 rows x 16 k
    #pragma unroll
    for (int vv2=0; vv2<8; ++vv2){
      float4 wa = *(const float4*)(wp);
      float4 wb = *(const float4*)(wp + H_N);
      wp += 2*H_N;
      double a0=(double)wa.x, a1=(double)wa.y, a2=(double)wa.z, a3=(double)wa.w;
      double b0d=(double)wb.x, b1d=(double)wb.y, b2d=(double)wb.z, b3d=(double)wb.w;
      #pragma unroll
      for (int r8=0;r8<8;++r8){
        double2 xp = *(const double2*)(xrow + r8*16 + vv2*2);  // broadcast, no conflict
        acc[r8][0] = fma(xp.x, a0, acc[r8][0]);
        acc[r8][1] = fma(xp.x, a1, acc[r8][1]);
        acc[r8][2] = fma(xp.x, a2, acc[r8][2]);
        acc[r8][3] = fma(xp.x, a3, acc[r8][3]);
        acc[r8][0] = fma(xp.y, b0d, acc[r8][0]);
        acc[r8][1] = fma(xp.y, b1d, acc[r8][1]);
        acc[r8][2] = fma(xp.y, b2d, acc[r8][2]);
        acc[r8][3] = fma(xp.y, b3d, acc[r8][3]);
      }
    }
    __syncthreads();
  }
  #pragma unroll
  for (int r8=0;r8<8;++r8){
    int r = rg*8 + r8;
    #pragma unroll
    for (int j=0;j<4;++j){
      int c = c0 + j;
      float m1 = (float)(acc[r8][j] + (double)be[c]);   // f32 array boundary
      enc_s[r*257 + c] = (float)tanh((double)m1);        // libm tanh, f32 store
    }
  }
  __syncthreads();
  if (tid < 128){
    int r = tid >> 2, q = tid & 3;
    double s = 0.0;
    for (int h=0; h<H_N; ++h)
      s = fma((double)enc_s[r*257+h], (double)W1[h*4+q], s);
    t2_s[r*4+q] = (float)s;                              // f32 array boundary
  }
  __syncthreads();
  float nbeta = -(float)log1p(exp((double)invt[0]));     // -softplus(inv_temp)
  for (int p=0;p<2;++p){
    int id = tid + p*256;
    int r = id >> 4, e = id & 15;
    float y = 0.0f;
    #pragma unroll
    for (int q=0;q<4;++q){
      float a1f = t2_s[r*4+q] + W1[(H_N+e)*4+q];
      float a2f = a1f + b1[q];
      float hin  = (float)tanh((double)a2f);             // inner tanh
      float hout = (float)tanh((double)hin);             // outer tanh (nested in ref)
      y = y + hout * w2[q];
    }
    float yb = y + b2[0];
    float en = 3.0f * (float)tanh((double)yb);
    size_t gi = (size_t)(row0 + r)*E_N + e;
    energ[gi] = en;
    logit[gi] = nbeta * en;
  }
}

// ---------------- SAMP: annealed Metropolis chain + one-hot write ----------------
__global__ __launch_bounds__(256) void samp_kernel(
    const float* __restrict__ energ, const unsigned* __restrict__ wsu,
    float* __restrict__ probs){
#pragma clang fp contract(off)
  __shared__ float se[256*16];
  const int lt = threadIdx.x;
  const int b = blockIdx.x*256 + lt;

  unsigned flag = wsu[502];
  if (flag != 0u){
    float c = 0.10f + 0.05f * (float)flag;
    float* op = probs + (size_t)b*E_N;
    #pragma unroll
    for (int j0=0; j0<16; j0+=4){
      float4 r; r.x=c; r.y=c; r.z=c; r.w=c;
      *(float4*)(op + j0) = r;
    }
    return;
  }

  float4* sv = (float4*)(se + lt*16);
  const float4* er = (const float4*)(energ + (size_t)b*E_N);
  sv[0]=er[0]; sv[1]=er[1]; sv[2]=er[2]; sv[3]=er[3];

  uint32_t k20 = wsu[500], k21 = wsu[501];
  uint32_t cur = rbits(k20, k21, (uint32_t)b) & 15u;

  for (int t=0; t<100; ++t){
    uint32_t pa=wsu[t*5+0], pb=wsu[t*5+1], ua=wsu[t*5+2], ub=wsu[t*5+3];
    float T = __uint_as_float(wsu[t*5+4]);
    uint32_t prop = rbits(pa, pb, (uint32_t)b) & 15u;
    uint32_t ru   = rbits(ua, ub, (uint32_t)b);
    float u = __uint_as_float((ru >> 9) | 0x3f800000u) - 1.0f;
    float ec = se[lt*16 + (int)cur];
    float ep = se[lt*16 + (int)prop];
    float d = ep - ec;
    float z = (-d) / T;
    z = fminf(z, 0.0f);
    float a = (float)exp((double)z);     // correctly-rounded f32 exp
    cur = (u < a) ? prop : cur;
  }
  float* op = probs + (size_t)b*E_N;
  #pragma unroll
  for (int j0=0; j0<16; j0+=4){
    float4 r;
    r.x = (cur == (uint32_t)(j0+0)) ? 1.0f : 0.0f;
    r.y = (cur == (uint32_t)(j0+1)) ? 1.0f : 0.0f;
    r.z = (cur == (uint32_t)(j0+2)) ? 1.0f : 0.0f;
    r.w = (cur == (uint32_t)(j0+3)) ? 1.0f : 0.0f;
    *(float4*)(op + j0) = r;
  }
}

extern "C" void kernel_launch(void* const* d_in, const int* in_sizes, int n_in,
                              void* d_out, int out_size, void* d_ws, size_t ws_size,
                              hipStream_t stream) {
  const float* x   = (const float*)d_in[0];
  const float* We  = (const float*)d_in[1];
  const float* be  = (const float*)d_in[2];
  const float* W1  = (const float*)d_in[3];
  const float* b1  = (const float*)d_in[4];
  const float* w2  = (const float*)d_in[5];
  const float* b2  = (const float*)d_in[6];
  const float* itp = (const float*)d_in[7];
  float* out = (float*)d_out;
  float* probs = out;
  float* energ = out + (size_t)B_N*E_N;
  float* logit = out + 2*(size_t)B_N*E_N;
  unsigned* wsu = (unsigned*)d_ws;

  float log_ratio = (float)log((double)((float)0.1));

  hipLaunchKernelGGL(s0_kernel, dim3(1), dim3(128), 0, stream, wsu, log_ratio);
  hipLaunchKernelGGL(ke_kernel, dim3(B_N/32), dim3(256), 0, stream,
                     x, We, be, W1, b1, w2, b2, itp, energ, logit);
  hipLaunchKernelGGL(samp_kernel, dim3(B_N/256), dim3(256), 0, stream,
                     energ, wsu, probs);
}

// Round 8
// 671.953 us; speedup vs baseline: 1.6397x; 1.3619x over previous
//
#include <hip/hip_runtime.h>
#include <math.h>
#include <stdint.h>

#define B_N 32768
#define V_N 2048
#define H_N 256
#define E_N 16
#define Q_N 4

#define KT 64
#define NSTRIP (V_N/KT)   // 32

// RNG variant: 1 = jax_threefry_partitionable. Proven passing r4-r6.
#define RNG_PART 1

typedef double f64x4 __attribute__((ext_vector_type(4)));

// ---------------- Threefry2x32 (JAX-exact, 20 rounds; KAT-verified on HW r2) ----------------
#define TF_R(x0,x1,r) { x0 += x1; x1 = ((x1 << (r)) | (x1 >> (32-(r)))); x1 ^= x0; }

__device__ __forceinline__ void tf_block(uint32_t k0, uint32_t k1, uint32_t &x0, uint32_t &x1){
  uint32_t k2 = k0 ^ k1 ^ 0x1BD11BDAu;
  x0 += k0; x1 += k1;
  TF_R(x0,x1,13) TF_R(x0,x1,15) TF_R(x0,x1,26) TF_R(x0,x1,6)
  x0 += k1; x1 += k2 + 1u;
  TF_R(x0,x1,17) TF_R(x0,x1,29) TF_R(x0,x1,16) TF_R(x0,x1,24)
  x0 += k2; x1 += k0 + 2u;
  TF_R(x0,x1,13) TF_R(x0,x1,15) TF_R(x0,x1,26) TF_R(x0,x1,6)
  x0 += k0; x1 += k1 + 3u;
  TF_R(x0,x1,17) TF_R(x0,x1,29) TF_R(x0,x1,16) TF_R(x0,x1,24)
  x0 += k1; x1 += k2 + 4u;
  TF_R(x0,x1,13) TF_R(x0,x1,15) TF_R(x0,x1,26) TF_R(x0,x1,6)
  x0 += k2; x1 += k0 + 5u;
}

__device__ __forceinline__ int run_kats(){
  uint32_t x0, x1;
  x0 = 0u; x1 = 0u;
  tf_block(0u, 0u, x0, x1);
  if (x0 != 0x6b200159u || x1 != 0x99ba4efeu) return 1;
  x0 = 0xFFFFFFFFu; x1 = 0xFFFFFFFFu;
  tf_block(0xFFFFFFFFu, 0xFFFFFFFFu, x0, x1);
  if (x0 != 0x1cb996fcu || x1 != 0xbb002be7u) return 2;
  x0 = 0x243f6a88u; x1 = 0x85a308d3u;
  tf_block(0x13198a2eu, 0x03707344u, x0, x1);
  if (x0 != 0xc4923a9cu || x1 != 0x483df7a0u) return 3;
  return 0;
}

// random_bits(key, 32, (32768,))[b]
__device__ __forceinline__ uint32_t rbits(uint32_t ka, uint32_t kb, uint32_t b){
#if RNG_PART
  uint32_t x0 = 0u, x1 = b;
  tf_block(ka, kb, x0, x1);
  return x0 ^ x1;
#else
  uint32_t i = b & 16383u;
  uint32_t x0 = i, x1 = i + 16384u;
  tf_block(ka, kb, x0, x1);
  return (b < 16384u) ? x0 : x1;
#endif
}

// asymmetric MFMA-test reference matrices
__device__ __forceinline__ double Aref(int i, int k){ return 0.5 + 0.03*i - 0.7*k + 0.011*i*k; }
__device__ __forceinline__ double Bref(int k, int j){ return 1.1*k - 0.17*j + 0.019*j*k + 0.23; }

// ---------------- S0: keys + T schedule + KAT flag + MFMA-f64 8-combo calibration ----------------
__global__ void s0_kernel(unsigned* __restrict__ wsu, float log_ratio){
#pragma clang fp contract(off)
  int t = threadIdx.x;

  // Calibrate v_mfma_f64_16x16x4 layout: combo = swap | drow<<1 | dt<<2.
  // Canonical frags: aval = A[m=l&15][k=l>>4], bval = B[k=l>>4][n=l&15].
  if (t < 64){
    int l = t;
    int lr = l & 15, g = l >> 4;
    double aval = Aref(lr, g);
    double bval = Bref(g, lr);
    int found = 8;
    for (int combo = 0; combo < 8; ++combo){
      int swap = combo & 1, drow = (combo>>1)&1, dt = (combo>>2)&1;
      f64x4 c = {0.0,0.0,0.0,0.0};
      if (swap) c = __builtin_amdgcn_mfma_f64_16x16x4f64(bval, aval, c, 0,0,0);
      else      c = __builtin_amdgcn_mfma_f64_16x16x4f64(aval, bval, c, 0,0,0);
      int bad = 0;
      #pragma unroll
      for (int r=0;r<4;++r){
        int f = drow ? (g + 4*r) : (4*g + r);
        int row = dt ? lr : f;
        int col = dt ? f  : lr;
        double e = 0.0;
        #pragma unroll
        for (int k=0;k<4;++k) e += Aref(row,k)*Bref(k,col);
        if (fabs(c[r] - e) > 1e-9) bad = 1;
      }
      if (__ballot(bad != 0) == 0ull){ found = combo; break; }
    }
    if (l == 0) wsu[503] = (unsigned)found;
  }

  uint32_t ka = 0u, kb = 1u;  // jax.random.key(1) == (0,1)
  uint32_t kinit0, kinit1, kl0, kl1;
#if RNG_PART
  { uint32_t a0=0u,a1=0u; tf_block(ka,kb,a0,a1); kinit0=a0; kinit1=a1; }
  { uint32_t a0=0u,a1=1u; tf_block(ka,kb,a0,a1); kl0=a0; kl1=a1; }
#else
  { uint32_t c00=0u,c01=2u; tf_block(ka,kb,c00,c01);
    uint32_t c10=1u,c11=3u; tf_block(ka,kb,c10,c11);
    kinit0=c00; kinit1=c10; kl0=c01; kl1=c11; }
#endif
  if (t == 0){
    wsu[502] = (unsigned)run_kats();
#if RNG_PART
    uint32_t x0=0u, x1=1u; tf_block(kinit0,kinit1,x0,x1);
    wsu[500]=x0; wsu[501]=x1;
#else
    uint32_t e00=0u,e01=2u; tf_block(kinit0,kinit1,e00,e01);
    uint32_t e10=1u,e11=3u; tf_block(kinit0,kinit1,e10,e11);
    wsu[500]=e01; wsu[501]=e11;
#endif
  }
  if (t < 100){
    uint32_t kt0=0u, kt1=(uint32_t)t; tf_block(kl0,kl1,kt0,kt1);   // fold_in(kloop, t)
    uint32_t q0, q1, v0, v1;
#if RNG_PART
    uint32_t p0=0u,p1=0u; tf_block(kt0,kt1,p0,p1);    // kp = split(kt)[0]
    uint32_t u0=0u,u1=1u; tf_block(kt0,kt1,u0,u1);    // ku = split(kt)[1]
    { uint32_t a=0u,b=1u; tf_block(p0,p1,a,b); q0=a; q1=b; }   // split(kp)[1]
    { uint32_t a=0u,b=1u; tf_block(u0,u1,a,b); v0=a; v1=b; }   // fold_in(ku,1)
#else
    uint32_t d00=0u,d01=2u; tf_block(kt0,kt1,d00,d01);
    uint32_t d10=1u,d11=3u; tf_block(kt0,kt1,d10,d11);
    uint32_t kp0=d00, kp1=d10, ku0=d01, ku1k=d11;
    uint32_t e00=0u,e01=2u; tf_block(kp0,kp1,e00,e01);
    uint32_t e10=1u,e11=3u; tf_block(kp0,kp1,e10,e11);
    q0=e01; q1=e11;
    { uint32_t a=0u,b=1u; tf_block(ku0,ku1k,a,b); v0=a; v1=b; }
#endif
    float fr = (float)t / 99.0f;
    float arg = log_ratio * fr;
    float T = (float)exp((double)arg);
    wsu[t*5+0]=q0; wsu[t*5+1]=q1; wsu[t*5+2]=v0; wsu[t*5+3]=v1;
    wsu[t*5+4]=__float_as_uint(T);
  }
}

// ---------------- MFMA GEMM strips (x@We), templated on operand order ----------------
template<bool SWAP>
__device__ __forceinline__ void mfma_strips(
    const float* __restrict__ x, const float* __restrict__ We,
    double* xs0, double* xs1, f64x4 acc[2][4],
    int tid, int wave, int lr, int lk, int row0)
{
  #pragma unroll
  for (int i=0;i<8;++i){
    int e = tid + i*256; int row = e >> 6; int k = e & 63;
    xs0[row*65 + k] = (double)x[(size_t)(row0+row)*V_N + k];
  }
  __syncthreads();

  for (int s=0; s<NSTRIP; ++s){
    double* cur = (s & 1) ? xs1 : xs0;
    double* nxt = (s & 1) ? xs0 : xs1;

    float xr[8];
    if (s+1 < NSTRIP){
      #pragma unroll
      for (int i=0;i<8;++i){
        int e = tid + i*256; int row = e >> 6; int k = e & 63;
        xr[i] = x[(size_t)(row0+row)*V_N + (size_t)(s+1)*KT + k];
      }
    }

    const float* Bp = We + ((size_t)s*KT + lk)*H_N + wave*64 + lr;
    #pragma unroll 4
    for (int kk=0; kk<16; ++kk){
      double a0 = cur[(     lr)*65 + kk*4 + lk];
      double a1 = cur[(16 + lr)*65 + kk*4 + lk];
      #pragma unroll
      for (int j=0;j<4;++j){
        double bv = (double)Bp[j*16];
        if (SWAP){
          acc[0][j] = __builtin_amdgcn_mfma_f64_16x16x4f64(bv, a0, acc[0][j], 0,0,0);
          acc[1][j] = __builtin_amdgcn_mfma_f64_16x16x4f64(bv, a1, acc[1][j], 0,0,0);
        } else {
          acc[0][j] = __builtin_amdgcn_mfma_f64_16x16x4f64(a0, bv, acc[0][j], 0,0,0);
          acc[1][j] = __builtin_amdgcn_mfma_f64_16x16x4f64(a1, bv, acc[1][j], 0,0,0);
        }
      }
      Bp += 4*H_N;
    }

    if (s+1 < NSTRIP){
      #pragma unroll
      for (int i=0;i<8;++i){
        int e = tid + i*256; int row = e >> 6; int k = e & 63;
        nxt[row*65 + k] = (double)xr[i];
      }
    }
    __syncthreads();
  }
}

// ---------------- VALU GEMM fallback (bit-identical to r6 pass) + enc write ----------------
__device__ __forceinline__ void valu_gemm_and_enc(
    const float* __restrict__ x, const float* __restrict__ We, const float* __restrict__ be,
    double* xs_d, float* enc_s, int tid, int row0)
{
  const int rg = tid >> 6;
  const int c0 = (tid & 63) * 4;
  double acc[8][4];
  #pragma unroll
  for (int r=0;r<8;++r){ acc[r][0]=0.0; acc[r][1]=0.0; acc[r][2]=0.0; acc[r][3]=0.0; }

  const int fr0 = tid >> 4, fc0 = tid & 15;
  const int fr1 = (tid+256) >> 4;
  const size_t xbase = (size_t)row0 * V_N;

  for (int v0=0; v0<V_N; v0+=16){
    xs_d[tid]       = (double)x[xbase + (size_t)fr0*V_N + v0 + fc0];
    xs_d[tid + 256] = (double)x[xbase + (size_t)fr1*V_N + v0 + fc0];
    __syncthreads();
    const float* wp = We + (size_t)v0*H_N + c0;
    const double* xrow = xs_d + rg*128;
    #pragma unroll
    for (int vv2=0; vv2<8; ++vv2){
      float4 wa = *(const float4*)(wp);
      float4 wb = *(const float4*)(wp + H_N);
      wp += 2*H_N;
      double a0=(double)wa.x, a1=(double)wa.y, a2=(double)wa.z, a3=(double)wa.w;
      double b0d=(double)wb.x, b1d=(double)wb.y, b2d=(double)wb.z, b3d=(double)wb.w;
      #pragma unroll
      for (int r8=0;r8<8;++r8){
        double2 xp = *(const double2*)(xrow + r8*16 + vv2*2);
        acc[r8][0] = fma(xp.x, a0, acc[r8][0]);
        acc[r8][1] = fma(xp.x, a1, acc[r8][1]);
        acc[r8][2] = fma(xp.x, a2, acc[r8][2]);
        acc[r8][3] = fma(xp.x, a3, acc[r8][3]);
        acc[r8][0] = fma(xp.y, b0d, acc[r8][0]);
        acc[r8][1] = fma(xp.y, b1d, acc[r8][1]);
        acc[r8][2] = fma(xp.y, b2d, acc[r8][2]);
        acc[r8][3] = fma(xp.y, b3d, acc[r8][3]);
      }
    }
    __syncthreads();
  }
  #pragma unroll
  for (int r8=0;r8<8;++r8){
    int r = rg*8 + r8;
    #pragma unroll
    for (int j=0;j<4;++j){
      int c = c0 + j;
      float m1 = (float)(acc[r8][j] + (double)be[c]);
      enc_s[r*257 + c] = (float)tanh((double)m1);
    }
  }
}

// ---------------- KE: fused energies pipeline ----------------
__global__ __launch_bounds__(256) void ke_kernel(
    const float* __restrict__ x, const float* __restrict__ We,
    const float* __restrict__ be, const float* __restrict__ W1,
    const float* __restrict__ b1, const float* __restrict__ w2,
    const float* __restrict__ b2, const float* __restrict__ invt,
    const unsigned* __restrict__ wsu,
    float* __restrict__ energ, float* __restrict__ logit){
#pragma clang fp contract(off)
  __shared__ double smem[2*32*65];          // 33.3 KB; enc_s aliases this after the GEMM
  __shared__ float t2_s[32*4];
  double* xs0 = smem;
  double* xs1 = smem + 32*65;
  float* enc_s = (float*)smem;

  const int tid = threadIdx.x;
  const int wave = tid >> 6;
  const int l = tid & 63;
  const int lr = l & 15;
  const int lk = l >> 4;
  const int row0 = blockIdx.x * 32;

  const unsigned combo = wsu[503];   // uniform

  if (combo < 8u){
    f64x4 acc[2][4];
    #pragma unroll
    for (int rt=0;rt<2;++rt)
      #pragma unroll
      for (int j=0;j<4;++j){ acc[rt][j][0]=0.0; acc[rt][j][1]=0.0; acc[rt][j][2]=0.0; acc[rt][j][3]=0.0; }

    if (combo & 1u) mfma_strips<true >(x, We, xs0, xs1, acc, tid, wave, lr, lk, row0);
    else            mfma_strips<false>(x, We, xs0, xs1, acc, tid, wave, lr, lk, row0);

    const int drow = (combo >> 1) & 1, dt = (combo >> 2) & 1;
    // D tile element (m,n): m -> x-row-in-tile, n -> We-col-in-tile
    #pragma unroll
    for (int rt=0;rt<2;++rt){
      #pragma unroll
      for (int j=0;j<4;++j){
        #pragma unroll
        for (int r=0;r<4;++r){
          int f = drow ? (lk + 4*r) : (4*lk + r);
          int m = dt ? lr : f;
          int n = dt ? f  : lr;
          int row = rt*16 + m;
          int col = wave*64 + j*16 + n;
          float m1 = (float)(acc[rt][j][r] + (double)be[col]);   // f32 boundary
          enc_s[row*257 + col] = (float)tanh((double)m1);        // libm tanh
        }
      }
    }
  } else {
    valu_gemm_and_enc(x, We, be, smem, enc_s, tid, row0);
  }
  __syncthreads();

  if (tid < 128){
    int r = tid >> 2, q = tid & 3;
    double s = 0.0;
    for (int h=0; h<H_N; ++h)
      s = fma((double)enc_s[r*257+h], (double)W1[h*4+q], s);
    t2_s[r*4+q] = (float)s;                              // f32 boundary
  }
  __syncthreads();
  float nbeta = -(float)log1p(exp((double)invt[0]));     // -softplus(inv_temp)
  for (int p=0;p<2;++p){
    int id = tid + p*256;
    int r = id >> 4, e = id & 15;
    float y = 0.0f;
    #pragma unroll
    for (int q=0;q<4;++q){
      float a1f = t2_s[r*4+q] + W1[(H_N+e)*4+q];
      float a2f = a1f + b1[q];
      float hin  = (float)tanh((double)a2f);             // inner tanh
      float hout = (float)tanh((double)hin);             // outer tanh (nested in ref)
      y = y + hout * w2[q];
    }
    float yb = y + b2[0];
    float en = 3.0f * (float)tanh((double)yb);
    size_t gi = (size_t)(row0 + r)*E_N + e;
    energ[gi] = en;
    logit[gi] = nbeta * en;
  }
}

// ---------------- SAMP: annealed Metropolis chain + one-hot write ----------------
__global__ __launch_bounds__(256) void samp_kernel(
    const float* __restrict__ energ, const unsigned* __restrict__ wsu,
    float* __restrict__ probs){
#pragma clang fp contract(off)
  __shared__ float se[256*16];
  const int lt = threadIdx.x;
  const int b = blockIdx.x*256 + lt;

  // KAT diagnostic channel only (MFMA layout failure now falls back, doesn't abort)
  unsigned flag = wsu[502];
  if (flag != 0u){
    float c = 0.10f + 0.05f * (float)flag;
    float* op = probs + (size_t)b*E_N;
    #pragma unroll
    for (int j0=0; j0<16; j0+=4){
      float4 r; r.x=c; r.y=c; r.z=c; r.w=c;
      *(float4*)(op + j0) = r;
    }
    return;
  }

  float4* sv = (float4*)(se + lt*16);
  const float4* er = (const float4*)(energ + (size_t)b*E_N);
  sv[0]=er[0]; sv[1]=er[1]; sv[2]=er[2]; sv[3]=er[3];

  uint32_t k20 = wsu[500], k21 = wsu[501];
  uint32_t cur = rbits(k20, k21, (uint32_t)b) & 15u;

  for (int t=0; t<100; ++t){
    uint32_t pa=wsu[t*5+0], pb=wsu[t*5+1], ua=wsu[t*5+2], ub=wsu[t*5+3];
    float T = __uint_as_float(wsu[t*5+4]);
    uint32_t prop = rbits(pa, pb, (uint32_t)b) & 15u;
    uint32_t ru   = rbits(ua, ub, (uint32_t)b);
    float u = __uint_as_float((ru >> 9) | 0x3f800000u) - 1.0f;
    float ec = se[lt*16 + (int)cur];
    float ep = se[lt*16 + (int)prop];
    float d = ep - ec;
    float z = (-d) / T;
    z = fminf(z, 0.0f);
    float a = (float)exp((double)z);     // correctly-rounded f32 exp
    cur = (u < a) ? prop : cur;
  }
  float* op = probs + (size_t)b*E_N;
  #pragma unroll
  for (int j0=0; j0<16; j0+=4){
    float4 r;
    r.x = (cur == (uint32_t)(j0+0)) ? 1.0f : 0.0f;
    r.y = (cur == (uint32_t)(j0+1)) ? 1.0f : 0.0f;
    r.z = (cur == (uint32_t)(j0+2)) ? 1.0f : 0.0f;
    r.w = (cur == (uint32_t)(j0+3)) ? 1.0f : 0.0f;
    *(float4*)(op + j0) = r;
  }
}

extern "C" void kernel_launch(void* const* d_in, const int* in_sizes, int n_in,
                              void* d_out, int out_size, void* d_ws, size_t ws_size,
                              hipStream_t stream) {
  const float* x   = (const float*)d_in[0];
  const float* We  = (const float*)d_in[1];
  const float* be  = (const float*)d_in[2];
  const float* W1  = (const float*)d_in[3];
  const float* b1  = (const float*)d_in[4];
  const float* w2  = (const float*)d_in[5];
  const float* b2  = (const float*)d_in[6];
  const float* itp = (const float*)d_in[7];
  float* out = (float*)d_out;
  float* probs = out;
  float* energ = out + (size_t)B_N*E_N;
  float* logit = out + 2*(size_t)B_N*E_N;
  unsigned* wsu = (unsigned*)d_ws;

  float log_ratio = (float)log((double)((float)0.1));

  hipLaunchKernelGGL(s0_kernel, dim3(1), dim3(128), 0, stream, wsu, log_ratio);
  hipLaunchKernelGGL(ke_kernel, dim3(B_N/32), dim3(256), 0, stream,
                     x, We, be, W1, b1, w2, b2, itp, wsu, energ, logit);
  hipLaunchKernelGGL(samp_kernel, dim3(B_N/256), dim3(256), 0, stream,
                     energ, wsu, probs);
}